// Round 6
// baseline (275.237 us; speedup 1.0000x reference)
//
#include <hip/hip_runtime.h>

// B=16, T=2048, C=1024, H=64. out = causal-softmax(QK^T/8) V
// x fp32 [B,T,C]; Wq/Wk/Wv fp32 [C,H]; out fp32 [B,T,H].

#define B_ 16
#define T_ 2048
#define C_ 1024
#define H_ 64
#define QK_ELEMS (B_ * T_ * H_)

typedef float  f32x4  __attribute__((ext_vector_type(4)));
typedef __bf16 bf16x8 __attribute__((ext_vector_type(8)));
typedef __bf16 bf16x4 __attribute__((ext_vector_type(4)));

__device__ __forceinline__ void glds16(const void* g, void* l) {
    __builtin_amdgcn_global_load_lds(
        (const __attribute__((address_space(1))) void*)g,
        (__attribute__((address_space(3))) void*)l, 16, 0, 0);
}

// ---------------------------------------------------------------------------
// Kernel 0: W [C,H] fp32 (x3) -> Wt [192][1024] bf16 transposed + XOR-swizzled
// ---------------------------------------------------------------------------
__global__ __launch_bounds__(256) void wt_kernel(const float* __restrict__ Wq,
                                                 const float* __restrict__ Wk,
                                                 const float* __restrict__ Wv,
                                                 __bf16* __restrict__ Wt) {
    __shared__ float tl[64][65];
    const int mat = blockIdx.x >> 4;
    const int c0  = (blockIdx.x & 15) * 64;
    const float* W = (mat == 0) ? Wq : (mat == 1) ? Wk : Wv;
    const int t  = threadIdx.x;
    const int r4 = t >> 6;
    const int cc = t & 63;
#pragma unroll
    for (int i = 0; i < 16; i++) {
        const int c = r4 + i * 4;
        tl[c][cc] = W[(size_t)(c0 + c) * H_ + cc];
    }
    __syncthreads();
#pragma unroll
    for (int i = 0; i < 16; i++) {
        const int h = r4 + i * 4;
        const int cc2 = ((((cc >> 3) ^ (h & 7)) << 3) | (cc & 7));
        Wt[(size_t)mat * 65536 + (size_t)h * C_ + c0 + cc2] = (__bf16)tl[cc][h];
    }
}

// ---------------------------------------------------------------------------
// Kernel 1 (R5 rewrite): QKV projection, grid-limited-occupancy fix.
// Grid = 3 mats x 512 m-tiles = 1536 blocks, 256 threads each. Each block
// computes a 64x64 tile of ONE of Q/K/V (bid>>9 = mat, bid&511 = m-tile).
// All per-lane math is the verbatim restriction of the R4-verified kernel
// (wave w owns rows w*16+l15; nt<4; same fragment/swizzle formulas).
// A: direct-from-x register path (verified R4). B: glds16 dbuf, 16.4 KB LDS
// -> 6 blocks/CU resident = 24 waves/CU (was 8).
// ---------------------------------------------------------------------------
__global__ __launch_bounds__(256) void qkv_kernel(const float* __restrict__ x,
                                                  const __bf16* __restrict__ Wt,
                                                  __bf16* __restrict__ Qw,
                                                  __bf16* __restrict__ Kw,
                                                  __bf16* __restrict__ Vtw) {
    __shared__ __align__(16) __bf16 Blds[2][64 * 64];

    const int tid  = threadIdx.x;
    const int w    = tid >> 6;            // 0..3
    const int lane = tid & 63;
    const int quad = lane >> 4;
    const int l15  = lane & 15;
    const int bid  = blockIdx.x;
    const int mat  = bid >> 9;            // 0=Q, 1=K, 2=V
    const int m0   = (bid & 511) * 64;
    const int wm   = w * 16;              // wave's 16-row tile

    f32x4 acc[4];
#pragma unroll
    for (int i = 0; i < 4; i++) acc[i] = (f32x4){0.f, 0.f, 0.f, 0.f};

    // A: lane owns row m0+wm+l15 (verified direct-reg path, single row-tile)
    const float* xA = x + (size_t)(m0 + wm + l15) * C_ + quad * 8;
    float4 a[4];                          // one K-step: 2 kh x 2 halves
    auto loadA = [&](int k0) {
#pragma unroll
        for (int kh = 0; kh < 2; kh++) {
            a[kh * 2 + 0] = *(const float4*)(xA + k0 + kh * 32);
            a[kh * 2 + 1] = *(const float4*)(xA + k0 + kh * 32 + 4);
        }
    };

    // B: this mat's 64 Wt rows; wave w stages rows wm..wm+15 (2 glds16)
    const __bf16* bsrc = Wt + (size_t)mat * 65536
                            + (size_t)(wm + (lane >> 3)) * C_ + (lane & 7) * 8;
    auto asyncB = [&](int k0, int buf) {
        __bf16* dst = &Blds[buf][wm * 64];
        const __bf16* src = bsrc + k0;
#pragma unroll
        for (int i = 0; i < 2; i++)
            glds16(src + (size_t)i * 8 * C_, dst + i * 8 * 64);
    };

    asyncB(0, 0);
    loadA(0);

    for (int k = 0; k < 16; k++) {
        __syncthreads();                  // drains asyncB(k) + loadA(k)

        // consume this step's A regs first (SSA; then re-issue below)
        bf16x8 af[2];
#pragma unroll
        for (int kh = 0; kh < 2; kh++) {
            const float4 p = a[kh * 2 + 0];
            const float4 q = a[kh * 2 + 1];
            bf16x8 v;
            v[0]=(__bf16)p.x; v[1]=(__bf16)p.y; v[2]=(__bf16)p.z; v[3]=(__bf16)p.w;
            v[4]=(__bf16)q.x; v[5]=(__bf16)q.y; v[6]=(__bf16)q.z; v[7]=(__bf16)q.w;
            af[kh] = v;
        }

        const int kn = k + 1;
        if (kn < 16) { asyncB(kn * 64, kn & 1); loadA(kn * 64); }
        const int buf = k & 1;
#pragma unroll
        for (int kh = 0; kh < 2; kh++) {
            const int ch8 = ((((kh << 2) + quad) ^ (l15 & 7)) << 3);
#pragma unroll
            for (int nt = 0; nt < 4; nt++) {
                bf16x8 bfr = *(const bf16x8*)&Blds[buf][(nt * 16 + l15) * 64 + ch8];
                acc[nt] = __builtin_amdgcn_mfma_f32_16x16x32_bf16(af[kh], bfr, acc[nt], 0, 0, 0);
            }
        }
    }

    // ---- epilogue by mat (index formulas verbatim from the verified kernel)
    const int row0 = m0 + wm + quad * 4;
    if (mat == 0) {
#pragma unroll
        for (int nt = 0; nt < 4; nt++) {
            const int col = nt * 16 + l15;
            const f32x4 acv = acc[nt];
#pragma unroll
            for (int r = 0; r < 4; r++)
                Qw[(size_t)(row0 + r) * H_ + col] = (__bf16)acv[r];
        }
    } else if (mat == 1) {
#pragma unroll
        for (int nt = 0; nt < 4; nt++) {
            const int h = nt * 16 + l15;
            const f32x4 acv = acc[nt];
#pragma unroll
            for (int r = 0; r < 4; r++) {
                const int row = row0 + r;
                const int hs  = (((h >> 3) ^ (row & 7)) << 3) | (h & 7);
                Kw[(size_t)row * H_ + hs] = (__bf16)acv[r];
            }
        }
    } else {
        // V: transpose via LDS bounce. Vt_l spans past Blds[0] into Blds[1],
        // so a barrier first ensures all waves are done reading Blds[1].
        __syncthreads();
        __bf16* Vt_l = &Blds[0][0];       // [64 h][72]
        const int t0 = wm + quad * 4;
#pragma unroll
        for (int nt = 0; nt < 4; nt++) {
            const int h = nt * 16 + l15;
            const f32x4 acv = acc[nt];
            bf16x4 pv;
            pv[0]=(__bf16)acv[0]; pv[1]=(__bf16)acv[1];
            pv[2]=(__bf16)acv[2]; pv[3]=(__bf16)acv[3];
            *(bf16x4*)&Vt_l[h * 72 + t0] = pv;
        }
        __syncthreads();
        const int bb   = m0 >> 11;
        const int tblk = m0 & 2047;
#pragma unroll
        for (int i = 0; i < 2; i++) {
            const int hh = wm + i * 8 + (lane >> 3);
            const int cs = (((lane & 7) ^ (lane >> 3)) << 3);     // src chunk
            *(bf16x8*)(Vtw + (((size_t)(bb * H_ + hh)) << 11) + tblk + ((lane & 7) << 3)) =
                *(const bf16x8*)&Vt_l[hh * 72 + cs];
        }
    }
}

// ---------------------------------------------------------------------------
// Kernel 2: paired causal flash attention (verified dbuf structure).
// ---------------------------------------------------------------------------
#define SCALE_LOG2E 0.18033688011112042f   // (1/sqrt(64)) * log2(e)

__global__ __launch_bounds__(256) void attn_kernel(const __bf16* __restrict__ Qw,
                                                   const __bf16* __restrict__ Kw,
                                                   const __bf16* __restrict__ Vtw,
                                                   float* __restrict__ Opart,
                                                   float* __restrict__ Lpart) {
    __shared__ __align__(16) __bf16 Klds[2][64 * 64];
    __shared__ __align__(16) __bf16 Vlds[2][64 * 64];
    __shared__ __align__(16) __bf16 Plds[2][4][16 * 72];

    const int tid  = threadIdx.x;
    const int w    = tid >> 6;
    const int lane = tid & 63;
    const int quad = lane >> 4;
    const int l15  = lane & 15;

    const int b   = blockIdx.x & 15;
    const int cid = blockIdx.x >> 4;          // 0..39, heavy chunks first
    int i, ci;
    if (cid < 16)      { i = 15 - (cid >> 2); ci = cid & 3; }
    else if (cid < 28) { const int u = cid - 16; i = 11 - u / 3; ci = u % 3; }
    else if (cid < 36) { const int u = cid - 28; i = 7 - (u >> 1); ci = u & 1; }
    else               { i = 3 - (cid - 36); ci = 0; }

    const int jmax = 2 * i + 1;               // last key-tile of the pair
    const int j0 = ci * 8;
    const int j1 = (j0 + 8 < jmax + 1) ? j0 + 8 : jmax + 1;
    const int nj = j1 - j0;
    const int qA0 = 2 * i * 64;
    const size_t bT = (size_t)b * T_;

    // Q fragments (B-operand of S^T = K Q^T); two q-tiles
    const __bf16* qpA = Qw + (bT + qA0 + w * 16 + l15) * H_ + quad * 8;
    const bf16x8 qfA0 = *(const bf16x8*)qpA;
    const bf16x8 qfA1 = *(const bf16x8*)(qpA + 32);
    const bf16x8 qfB0 = *(const bf16x8*)(qpA + 64 * H_);
    const bf16x8 qfB1 = *(const bf16x8*)(qpA + 64 * H_ + 32);

    float lA = 0.f, lB = 0.f;
    f32x4 accA[4], accB[4];
#pragma unroll
    for (int nt = 0; nt < 4; nt++) {
        accA[nt] = (f32x4){0.f, 0.f, 0.f, 0.f};
        accB[nt] = (f32x4){0.f, 0.f, 0.f, 0.f};
    }

    // DMA staging: wave w, rep c -> row group g = w*2+c (8 rows, 1 KB)
    auto stage = [&](int ts0, int buf) {
        const __bf16* Ks = Kw + (bT + ts0) * H_;
        const __bf16* Vs = Vtw + (((size_t)(b * H_)) << 11) + ts0;
#pragma unroll
        for (int c = 0; c < 2; c++) {
            const int g   = w * 2 + c;
            const int row = g * 8 + (lane >> 3);
            const int cb  = (lane & 7) * 8;
            glds16(Ks + (size_t)row * H_ + cb, &Klds[buf][g * 512]);
            glds16(Vs + ((size_t)row << 11) + cb, &Vlds[buf][g * 512]);
        }
    };

    stage(j0 * 64, 0);

    for (int jj = 0; jj < nj; jj++) {
        const int j = j0 + jj;
        __syncthreads();                       // drains dma(buf) + prev compute
        if (jj + 1 < nj) stage((j + 1) * 64, (jj + 1) & 1);
        const int buf = jj & 1;
        const bool doA = (j <= 2 * i);
        const int ts0 = j * 64;
        const int qgA = qA0 + w * 16 + l15;

        // ---- per-nt: S^T tiles, exp, P bounce (keeps registers short-lived)
#pragma unroll
        for (int nt = 0; nt < 4; nt++) {
            const __bf16* kb = &Klds[buf][(nt * 16 + l15) * 64];
            bf16x8 kf0 = *(const bf16x8*)(kb + ((quad ^ (l15 & 7)) << 3));
            bf16x8 kf1 = *(const bf16x8*)(kb + (((4 + quad) ^ (l15 & 7)) << 3));
            const int key0 = ts0 + nt * 16 + quad * 4;

            if (doA) {
                f32x4 z = (f32x4){0.f, 0.f, 0.f, 0.f};
                z = __builtin_amdgcn_mfma_f32_16x16x32_bf16(kf0, qfA0, z, 0, 0, 0);
                z = __builtin_amdgcn_mfma_f32_16x16x32_bf16(kf1, qfA1, z, 0, 0, 0);
                bf16x4 pv;
#pragma unroll
                for (int r = 0; r < 4; r++) {
                    float e = exp2f(__builtin_fmaf(z[r], SCALE_LOG2E, -8.0f));
                    if (j == 2 * i && key0 + r > qgA) e = 0.f;
                    pv[r] = (__bf16)e;
                    lA += e;
                }
                *(bf16x4*)&Plds[0][w][l15 * 72 + nt * 16 + quad * 4] = pv;
            }
            {
                f32x4 z = (f32x4){0.f, 0.f, 0.f, 0.f};
                z = __builtin_amdgcn_mfma_f32_16x16x32_bf16(kf0, qfB0, z, 0, 0, 0);
                z = __builtin_amdgcn_mfma_f32_16x16x32_bf16(kf1, qfB1, z, 0, 0, 0);
                bf16x4 pv;
#pragma unroll
                for (int r = 0; r < 4; r++) {
                    float e = exp2f(__builtin_fmaf(z[r], SCALE_LOG2E, -8.0f));
                    if (j == jmax && key0 + r > qgA + 64) e = 0.f;
                    pv[r] = (__bf16)e;
                    lB += e;
                }
                *(bf16x4*)&Plds[1][w][l15 * 72 + nt * 16 + quad * 4] = pv;
            }
        }
        __asm__ __volatile__("s_waitcnt lgkmcnt(0)" ::: "memory");  // wave-local

        // ---- O += P V for both q-tiles (shared V frags)
        const __bf16* prA = &Plds[0][w][l15 * 72];
        const __bf16* prB = &Plds[1][w][l15 * 72];
        bf16x8 pfA0, pfA1;
        if (doA) {
            pfA0 = *(const bf16x8*)(prA + quad * 8);
            pfA1 = *(const bf16x8*)(prA + 32 + quad * 8);
        }
        bf16x8 pfB0 = *(const bf16x8*)(prB + quad * 8);
        bf16x8 pfB1 = *(const bf16x8*)(prB + 32 + quad * 8);
#pragma unroll
        for (int nt = 0; nt < 4; nt++) {
            const __bf16* vb = &Vlds[buf][(nt * 16 + l15) * 64];
            bf16x8 vf0 = *(const bf16x8*)(vb + ((quad ^ (l15 & 7)) << 3));
            bf16x8 vf1 = *(const bf16x8*)(vb + (((4 + quad) ^ (l15 & 7)) << 3));
            if (doA) {
                accA[nt] = __builtin_amdgcn_mfma_f32_16x16x32_bf16(pfA0, vf0, accA[nt], 0, 0, 0);
                accA[nt] = __builtin_amdgcn_mfma_f32_16x16x32_bf16(pfA1, vf1, accA[nt], 0, 0, 0);
            }
            accB[nt] = __builtin_amdgcn_mfma_f32_16x16x32_bf16(pfB0, vf0, accB[nt], 0, 0, 0);
            accB[nt] = __builtin_amdgcn_mfma_f32_16x16x32_bf16(pfB1, vf1, accB[nt], 0, 0, 0);
        }
    }

    // ---- write unnormalized partials for both q-tiles
    lA += __shfl_xor(lA, 16); lA += __shfl_xor(lA, 32);
    lB += __shfl_xor(lB, 16); lB += __shfl_xor(lB, 32);

    const int qiA = 2 * i;
    const int slotA = ((((b << 5) + qiA) << 2) + ci);
    const int slotB = ((((b << 5) + qiA + 1) << 2) + ci);
    float* OpA = Opart + (size_t)slotA * 4096;
    float* OpB = Opart + (size_t)slotB * 4096;
#pragma unroll
    for (int nt = 0; nt < 4; nt++)
#pragma unroll
        for (int r = 0; r < 4; r++) {
            const int o = (w * 16 + quad * 4 + r) * 64 + nt * 16 + l15;
            OpA[o] = accA[nt][r];
            OpB[o] = accB[nt][r];
        }
    if (quad == 0) {
        Lpart[slotA * 64 + w * 16 + l15] = lA;
        Lpart[slotB * 64 + w * 16 + l15] = lB;
    }
}

// ---------------------------------------------------------------------------
// Kernel 3: combine chunk partials. Block per (b, q-tile): out = sum(O)/sum(l)
// ---------------------------------------------------------------------------
__global__ __launch_bounds__(256) void reduce_kernel(const float* __restrict__ Opart,
                                                     const float* __restrict__ Lpart,
                                                     float* __restrict__ out) {
    const int b  = blockIdx.x & 15;
    const int qi = blockIdx.x >> 4;
    const int nc = ((qi & ~1) + 9) >> 3;      // chunks of the pair
    const int tid = threadIdx.x;
    const int q  = tid >> 2;
    const int hc = (tid & 3) * 16;
    const int sbase = ((b << 5) + qi) << 2;

    f32x4 s[4];
#pragma unroll
    for (int i = 0; i < 4; i++) s[i] = (f32x4){0.f, 0.f, 0.f, 0.f};
    float l = 0.f;
    for (int ci = 0; ci < nc; ci++) {
        const float* Op = Opart + (size_t)(sbase + ci) * 4096 + q * 64 + hc;
#pragma unroll
        for (int i = 0; i < 4; i++) s[i] += *(const f32x4*)(Op + i * 4);
        l += Lpart[(sbase + ci) * 64 + q];
    }
    const float inv = 1.f / l;
    float* o = out + ((size_t)b * T_ + qi * 64 + q) * H_ + hc;
#pragma unroll
    for (int i = 0; i < 4; i++) {
        f32x4 r = s[i] * inv;
        *(f32x4*)(o + i * 4) = r;
    }
}

// ---------------------------------------------------------------------------
extern "C" void kernel_launch(void* const* d_in, const int* in_sizes, int n_in,
                              void* d_out, int out_size, void* d_ws, size_t ws_size,
                              hipStream_t stream) {
    const float* x  = (const float*)d_in[0];
    const float* Wq = (const float*)d_in[1];
    const float* Wk = (const float*)d_in[2];
    const float* Wv = (const float*)d_in[3];
    float* out = (float*)d_out;

    __bf16* Qw  = (__bf16*)d_ws;
    __bf16* Kw  = Qw + QK_ELEMS;
    __bf16* Vtw = Kw + QK_ELEMS;
    __bf16* Wt  = Vtw + QK_ELEMS;
    float* Opart = (float*)((char*)d_ws + 16777216);
    float* Lpart = Opart + (size_t)2048 * 4096;

    wt_kernel<<<dim3(48), dim3(256), 0, stream>>>(Wq, Wk, Wv, Wt);
    qkv_kernel<<<dim3(1536), dim3(256), 0, stream>>>(x, Wt, Qw, Kw, Vtw);
    attn_kernel<<<dim3(640), dim3(256), 0, stream>>>(Qw, Kw, Vtw, Opart, Lpart);
    reduce_kernel<<<dim3(512), dim3(256), 0, stream>>>(Opart, Lpart, out);
}